// Round 1
// baseline (219.795 us; speedup 1.0000x reference)
//
#include <hip/hip_runtime.h>
#include <stdint.h>

#define Tdim 2048
#define Cdim 1024
#define C3   3072

typedef __attribute__((ext_vector_type(8))) short s16x8;
typedef __attribute__((ext_vector_type(4))) unsigned short u16x4;
typedef __attribute__((ext_vector_type(4))) float f32x4;

__device__ __forceinline__ unsigned short f2bf(float f) {
  uint32_t u = __float_as_uint(f);
  return (unsigned short)((u + 0x7FFFu + ((u >> 16) & 1u)) >> 16);
}
__device__ __forceinline__ float bf2f(unsigned short s) {
  return __uint_as_float(((uint32_t)s) << 16);
}

// ---------------- GroupNorm stats (two-stage, deterministic) ----------------
__global__ __launch_bounds__(256) void k_gn_partial(const float* __restrict__ x,
                                                    float* __restrict__ part) {
  int bid = blockIdx.x;             // [0,512) = bg*8 + tchunk
  int bg = bid >> 3, tc = bid & 7;
  const float* xp = x + ((size_t)(bg >> 5) * Cdim + (size_t)(bg & 31) * 32) * Tdim + tc * 256;
  int u = threadIdx.x;
  float s1 = 0.f, s2 = 0.f;
#pragma unroll
  for (int i = 0; i < 32; ++i) {
    int e = u + i * 256;            // 32c x 256t tile
    float v = xp[(size_t)(e >> 8) * Tdim + (e & 255)];
    s1 += v; s2 += v * v;
  }
  for (int m = 1; m < 64; m <<= 1) { s1 += __shfl_xor(s1, m); s2 += __shfl_xor(s2, m); }
  __shared__ float r1[4], r2[4];
  int w = u >> 6;
  if ((u & 63) == 0) { r1[w] = s1; r2[w] = s2; }
  __syncthreads();
  if (u == 0) {
    part[bid * 2]     = r1[0] + r1[1] + r1[2] + r1[3];
    part[bid * 2 + 1] = r2[0] + r2[1] + r2[2] + r2[3];
  }
}

__global__ void k_gn_final(const float* __restrict__ part, float* __restrict__ stats) {
  int bg = threadIdx.x;             // 64 threads
  float s1 = 0.f, s2 = 0.f;
  for (int j = 0; j < 8; ++j) { s1 += part[(bg * 8 + j) * 2]; s2 += part[(bg * 8 + j) * 2 + 1]; }
  const float inv = 1.f / 65536.f;
  float mean = s1 * inv;
  float var = s2 * inv - mean * mean;
  stats[bg * 2] = mean;
  stats[bg * 2 + 1] = rsqrtf(var + 1e-5f);
}

// ---------------- GroupNorm normalize + transpose -> xn_T (B,T,C) bf16 ----------------
__global__ __launch_bounds__(256) void k_gn_norm(const float* __restrict__ x,
                                                 const float* __restrict__ scale,
                                                 const float* __restrict__ bias,
                                                 const float* __restrict__ stats,
                                                 unsigned short* __restrict__ xnT) {
  int ti = blockIdx.x;              // T/64
  int g  = blockIdx.y;              // 32
  int b  = blockIdx.z;              // 2
  int u  = threadIdx.x;
  int bg = b * 32 + g;
  float mean = stats[bg * 2], rstd = stats[bg * 2 + 1];
  __shared__ float L[32][65];
  int c_loc = u >> 3, tc = (u & 7) * 8;
  int cg = g * 32 + c_loc;
  const float* xp = x + ((size_t)b * Cdim + cg) * Tdim + ti * 64 + tc;
  float sc = scale[cg] * rstd;
  float bi = bias[cg] - mean * sc;  // xn = x*sc + bi
#pragma unroll
  for (int i = 0; i < 8; ++i) L[c_loc][tc + i] = xp[i] * sc + bi;
  __syncthreads();
  int t_loc = u >> 2, cc = (u & 3) * 8;
  s16x8 ov;
#pragma unroll
  for (int i = 0; i < 8; ++i) ov[i] = (short)f2bf(L[cc + i][t_loc]);
  *(s16x8*)&xnT[((size_t)b * Tdim + ti * 64 + t_loc) * Cdim + g * 32 + cc] = ov;
}

// ---------------- f32 -> bf16 convert ----------------
__global__ __launch_bounds__(256) void k_convert(const float* __restrict__ in,
                                                 unsigned short* __restrict__ out, int n4) {
  int i = blockIdx.x * 256 + threadIdx.x;
  if (i >= n4) return;
  f32x4 v = *(const f32x4*)(in + (size_t)i * 4);
  u16x4 o;
  o[0] = f2bf(v[0]); o[1] = f2bf(v[1]); o[2] = f2bf(v[2]); o[3] = f2bf(v[3]);
  *(u16x4*)(out + (size_t)i * 4) = o;
}

// ---------------- GEMM: out[t][o] = sum_c A[t][c] * Bw[o][c] (+bias) ----------------
// EPI 0: store bf16 to outT (B,M,N)    [QKV]
// EPI 1: out[b][o][t] = acc + bias + xn_T[b][t][o], f32   [proj + residual]
template <int EPI>
__global__ __launch_bounds__(256) void k_gemm(const unsigned short* __restrict__ A,
                                              const unsigned short* __restrict__ Bw,
                                              const float* __restrict__ bias,
                                              unsigned short* __restrict__ outT,
                                              const unsigned short* __restrict__ xnT,
                                              float* __restrict__ out,
                                              int M, int N, int K) {
  int bx = blockIdx.x, by = blockIdx.y, bb = blockIdx.z;
  int tid = threadIdx.x;
  int lane = tid & 63, w = tid >> 6;
  int m0 = by * 128, n0 = bx * 128;
  const unsigned short* Ab = A + (size_t)bb * M * K;
  __shared__ short As[128][72];
  __shared__ short Bs[128][72];
  f32x4 acc[4][4] = {};
  int wm = (w >> 1) * 64, wn = (w & 1) * 64;
  int lr = lane & 15, lq = lane >> 4;

  for (int k0 = 0; k0 < K; k0 += 32) {
    s16x8 ra[2], rb[2];
#pragma unroll
    for (int p = 0; p < 2; ++p) {
      int u = tid + p * 256;
      int r = u >> 2, c = (u & 3) * 8;
      ra[p] = *(const s16x8*)(Ab + (size_t)(m0 + r) * K + k0 + c);
      rb[p] = *(const s16x8*)(Bw + (size_t)(n0 + r) * K + k0 + c);
    }
    __syncthreads();
#pragma unroll
    for (int p = 0; p < 2; ++p) {
      int u = tid + p * 256;
      int r = u >> 2, c = (u & 3) * 8;
      *(s16x8*)&As[r][c] = ra[p];
      *(s16x8*)&Bs[r][c] = rb[p];
    }
    __syncthreads();
    s16x8 af[4], bfr[4];
#pragma unroll
    for (int m = 0; m < 4; ++m) af[m] = *(const s16x8*)&As[wm + m * 16 + lr][lq * 8];
#pragma unroll
    for (int n = 0; n < 4; ++n) bfr[n] = *(const s16x8*)&Bs[wn + n * 16 + lr][lq * 8];
#pragma unroll
    for (int m = 0; m < 4; ++m)
#pragma unroll
      for (int n = 0; n < 4; ++n)
        acc[m][n] = __builtin_amdgcn_mfma_f32_16x16x32_bf16(af[m], bfr[n], acc[m][n], 0, 0, 0);
  }

  if constexpr (EPI == 0) {
#pragma unroll
    for (int n = 0; n < 4; ++n) {
      int col = n0 + wn + n * 16 + lr;
      float bv = bias[col];
#pragma unroll
      for (int m = 0; m < 4; ++m) {
        int rowb = m0 + wm + m * 16 + lq * 4;
#pragma unroll
        for (int j = 0; j < 4; ++j)
          outT[((size_t)bb * M + rowb + j) * N + col] = f2bf(acc[m][n][j] + bv);
      }
    }
  } else {
#pragma unroll
    for (int n = 0; n < 4; ++n) {
      int col = n0 + wn + n * 16 + lr;    // output channel o
      float bv = bias[col];
#pragma unroll
      for (int m = 0; m < 4; ++m) {
        int rowb = m0 + wm + m * 16 + lq * 4;  // t base (4 consecutive)
        f32x4 v;
#pragma unroll
        for (int j = 0; j < 4; ++j)
          v[j] = acc[m][n][j] + bv + bf2f(xnT[((size_t)bb * M + rowb + j) * Cdim + col]);
        *(f32x4*)&out[((size_t)bb * N + col) * M + rowb] = v;
      }
    }
  }
}

// ---------------- Flash attention ----------------
// qkvT: (B, T, 3C), per head h cols [h*192 .. h*192+192) = q|k|v each 64
// aT out: (B, T, C), c = h*64 + ch
__global__ __launch_bounds__(256) void k_attn(const unsigned short* __restrict__ qkvT,
                                              const unsigned short* __restrict__ biasbf,
                                              unsigned short* __restrict__ aT) {
  int ti = blockIdx.x;              // q tile (64 rows)
  int bh = blockIdx.y;              // b*16 + h
  int b = bh >> 4, h = bh & 15;
  int tid = threadIdx.x, lane = tid & 63, w = tid >> 6;
  int lr = lane & 15, lq = lane >> 4;
  int t0 = ti * 64;
  __shared__ short Ks[64][72];      // [s][c]
  __shared__ short Vs[64][72];      // [ch][s] (transposed)
  __shared__ short Ps[4][16][72];   // per-wave P tile [q][s]
  const unsigned short* hb = qkvT + ((size_t)b * Tdim) * C3 + h * 192;

  s16x8 qf[2];
  {
    int qrow = t0 + w * 16 + lr;
    const unsigned short* qp = hb + (size_t)qrow * C3 + lq * 8;
    qf[0] = *(const s16x8*)qp;
    qf[1] = *(const s16x8*)(qp + 32);
  }
  f32x4 oacc[4] = {};
  float mrow[4], lrow[4];
#pragma unroll
  for (int j = 0; j < 4; ++j) { mrow[j] = -1e30f; lrow[j] = 0.f; }

  for (int sj = 0; sj <= ti; ++sj) {
    int s0 = sj * 64;
    s16x8 kstg[2], vstg[2];
#pragma unroll
    for (int p = 0; p < 2; ++p) {
      int u = tid + p * 256;
      kstg[p] = *(const s16x8*)(hb + (size_t)(s0 + (u >> 3)) * C3 + 64 + (u & 7) * 8);
      vstg[p] = *(const s16x8*)(hb + (size_t)(s0 + (u & 63)) * C3 + 128 + (u >> 6) * 8);
    }
    __syncthreads();                 // prior iteration's LDS reads complete
#pragma unroll
    for (int p = 0; p < 2; ++p) {
      int u = tid + p * 256;
      *(s16x8*)&Ks[u >> 3][(u & 7) * 8] = kstg[p];
      int s = u & 63, c0 = (u >> 6) * 8;
#pragma unroll
      for (int i = 0; i < 8; ++i) Vs[c0 + i][s] = vstg[p][i];
    }
    __syncthreads();

    // S = Q K^T (16 q-rows per wave x 64 s)
    f32x4 sv[4] = {};
#pragma unroll
    for (int n = 0; n < 4; ++n) {
      s16x8 kf0 = *(const s16x8*)&Ks[n * 16 + lr][lq * 8];
      s16x8 kf1 = *(const s16x8*)&Ks[n * 16 + lr][32 + lq * 8];
      sv[n] = __builtin_amdgcn_mfma_f32_16x16x32_bf16(qf[0], kf0, sv[n], 0, 0, 0);
      sv[n] = __builtin_amdgcn_mfma_f32_16x16x32_bf16(qf[1], kf1, sv[n], 0, 0, 0);
    }
    // scale + bias + causal mask
#pragma unroll
    for (int n = 0; n < 4; ++n) {
      int s = s0 + n * 16 + lr;
#pragma unroll
      for (int j = 0; j < 4; ++j) {
        int q = t0 + w * 16 + lq * 4 + j;
        float xv = sv[n][j] * 0.125f + bf2f(biasbf[(size_t)q * Tdim + s]);
        sv[n][j] = (s <= q) ? xv : -1e30f;
      }
    }
    // online softmax (rows live in 16-lane groups: xor 1,2,4,8)
    float pmax[4];
#pragma unroll
    for (int j = 0; j < 4; ++j)
      pmax[j] = fmaxf(fmaxf(sv[0][j], sv[1][j]), fmaxf(sv[2][j], sv[3][j]));
#pragma unroll
    for (int m = 1; m < 16; m <<= 1)
#pragma unroll
      for (int j = 0; j < 4; ++j) pmax[j] = fmaxf(pmax[j], __shfl_xor(pmax[j], m));
    float alpha[4];
#pragma unroll
    for (int j = 0; j < 4; ++j) {
      float mn = fmaxf(mrow[j], pmax[j]);
      alpha[j] = __expf(mrow[j] - mn);
      mrow[j] = mn;
    }
    float rs[4] = {0.f, 0.f, 0.f, 0.f};
#pragma unroll
    for (int n = 0; n < 4; ++n)
#pragma unroll
      for (int j = 0; j < 4; ++j) {
        float p = __expf(sv[n][j] - mrow[j]);
        sv[n][j] = p;
        rs[j] += p;
      }
#pragma unroll
    for (int m = 1; m < 16; m <<= 1)
#pragma unroll
      for (int j = 0; j < 4; ++j) rs[j] += __shfl_xor(rs[j], m);
#pragma unroll
    for (int j = 0; j < 4; ++j) lrow[j] = lrow[j] * alpha[j] + rs[j];
#pragma unroll
    for (int f = 0; f < 4; ++f)
#pragma unroll
      for (int j = 0; j < 4; ++j) oacc[f][j] *= alpha[j];
    // P -> LDS (wave-private; in-wave ds dependency, no barrier needed)
#pragma unroll
    for (int n = 0; n < 4; ++n)
#pragma unroll
      for (int j = 0; j < 4; ++j)
        Ps[w][lq * 4 + j][n * 16 + lr] = (short)f2bf(sv[n][j]);
    // O += P V
#pragma unroll
    for (int ks = 0; ks < 2; ++ks) {
      s16x8 pa = *(const s16x8*)&Ps[w][lr][ks * 32 + lq * 8];
#pragma unroll
      for (int f = 0; f < 4; ++f) {
        s16x8 vb = *(const s16x8*)&Vs[f * 16 + lr][ks * 32 + lq * 8];
        oacc[f] = __builtin_amdgcn_mfma_f32_16x16x32_bf16(pa, vb, oacc[f], 0, 0, 0);
      }
    }
  }
  // write a_T
#pragma unroll
  for (int f = 0; f < 4; ++f) {
    int ch = h * 64 + f * 16 + lr;
#pragma unroll
    for (int j = 0; j < 4; ++j) {
      int t = t0 + w * 16 + lq * 4 + j;
      aT[((size_t)b * Tdim + t) * Cdim + ch] = f2bf(oacc[f][j] / lrow[j]);
    }
  }
}

extern "C" void kernel_launch(void* const* d_in, const int* in_sizes, int n_in,
                              void* d_out, int out_size, void* d_ws, size_t ws_size,
                              hipStream_t stream) {
  const float* x        = (const float*)d_in[0];
  // d_in[1] = mask (bool tril) — causality applied analytically, ignored
  const float* qk_bias  = (const float*)d_in[2];
  const float* gn_scale = (const float*)d_in[3];
  const float* gn_bias  = (const float*)d_in[4];
  const float* qkv_w    = (const float*)d_in[5];
  const float* qkv_b    = (const float*)d_in[6];
  const float* proj_w   = (const float*)d_in[7];
  const float* proj_b   = (const float*)d_in[8];
  float* out = (float*)d_out;

  char* ws = (char*)d_ws;
  unsigned short* xnT   = (unsigned short*)(ws);                      //  8 MiB (B,T,C)
  unsigned short* qkvT  = (unsigned short*)(ws + ( 8ull << 20));      // 24 MiB (B,T,3C)
  unsigned short* aT    = (unsigned short*)(ws + (32ull << 20));      //  8 MiB (B,T,C)
  unsigned short* wqkv  = (unsigned short*)(ws + (40ull << 20));      //  6 MiB (3C,C)
  unsigned short* wproj = (unsigned short*)(ws + (46ull << 20));      //  2 MiB (C,C)
  unsigned short* biasb = (unsigned short*)(ws + (48ull << 20));      //  8 MiB (T,T)
  float* part  = (float*)(ws + (56ull << 20));                        //  4 KiB
  float* stats = (float*)(ws + (56ull << 20) + 8192);                 //  512 B

  k_gn_partial<<<512, 256, 0, stream>>>(x, part);
  k_gn_final<<<1, 64, 0, stream>>>(part, stats);
  k_gn_norm<<<dim3(32, 32, 2), 256, 0, stream>>>(x, gn_scale, gn_bias, stats, xnT);

  k_convert<<<(3072 * 1024 / 4 + 255) / 256, 256, 0, stream>>>(qkv_w, wqkv, 3072 * 1024 / 4);
  k_convert<<<(1024 * 1024 / 4 + 255) / 256, 256, 0, stream>>>(proj_w, wproj, 1024 * 1024 / 4);
  k_convert<<<(2048 * 2048 / 4 + 255) / 256, 256, 0, stream>>>(qk_bias, biasb, 2048 * 2048 / 4);

  // QKV: M=T=2048, N=3C=3072, K=C=1024, batched over B
  k_gemm<0><<<dim3(24, 16, 2), 256, 0, stream>>>(xnT, wqkv, qkv_b, qkvT, nullptr, nullptr,
                                                 2048, 3072, 1024);
  k_attn<<<dim3(32, 32), 256, 0, stream>>>(qkvT, biasb, aT);
  // proj + residual: M=2048, N=1024, K=1024
  k_gemm<1><<<dim3(8, 16, 2), 256, 0, stream>>>(aT, wproj, proj_b, nullptr, xnT, out,
                                                2048, 1024, 1024);
}

// Round 2
// 204.390 us; speedup vs baseline: 1.0754x; 1.0754x over previous
//
#include <hip/hip_runtime.h>
#include <stdint.h>

#define Tdim 2048
#define Cdim 1024
#define C3   3072

typedef __attribute__((ext_vector_type(8))) short s16x8;
typedef __attribute__((ext_vector_type(4))) unsigned short u16x4;
typedef __attribute__((ext_vector_type(4))) float f32x4;
typedef __attribute__((ext_vector_type(16))) float f32x16;
typedef __attribute__((ext_vector_type(4))) int i32x4;

__device__ __forceinline__ unsigned short f2bf(float f) {
  uint32_t u = __float_as_uint(f);
  return (unsigned short)((u + 0x7FFFu + ((u >> 16) & 1u)) >> 16);
}
__device__ __forceinline__ float bf2f(unsigned short s) {
  return __uint_as_float(((uint32_t)s) << 16);
}
__device__ __forceinline__ uint32_t packbf(float lo, float hi) {
  return (uint32_t)f2bf(lo) | ((uint32_t)f2bf(hi) << 16);
}

// ---------------- GroupNorm stats (two-stage, deterministic) ----------------
__global__ __launch_bounds__(256) void k_gn_partial(const float* __restrict__ x,
                                                    float* __restrict__ part) {
  int bid = blockIdx.x;             // [0,512) = bg*8 + tchunk
  int bg = bid >> 3, tc = bid & 7;
  const float* xp = x + ((size_t)(bg >> 5) * Cdim + (size_t)(bg & 31) * 32) * Tdim + tc * 256;
  int u = threadIdx.x;
  float s1 = 0.f, s2 = 0.f;
#pragma unroll
  for (int i = 0; i < 32; ++i) {
    int e = u + i * 256;            // 32c x 256t tile
    float v = xp[(size_t)(e >> 8) * Tdim + (e & 255)];
    s1 += v; s2 += v * v;
  }
  for (int m = 1; m < 64; m <<= 1) { s1 += __shfl_xor(s1, m); s2 += __shfl_xor(s2, m); }
  __shared__ float r1[4], r2[4];
  int w = u >> 6;
  if ((u & 63) == 0) { r1[w] = s1; r2[w] = s2; }
  __syncthreads();
  if (u == 0) {
    part[bid * 2]     = r1[0] + r1[1] + r1[2] + r1[3];
    part[bid * 2 + 1] = r2[0] + r2[1] + r2[2] + r2[3];
  }
}

__global__ void k_gn_final(const float* __restrict__ part, float* __restrict__ stats) {
  int bg = threadIdx.x;             // 64 threads
  float s1 = 0.f, s2 = 0.f;
  for (int j = 0; j < 8; ++j) { s1 += part[(bg * 8 + j) * 2]; s2 += part[(bg * 8 + j) * 2 + 1]; }
  const float inv = 1.f / 65536.f;
  float mean = s1 * inv;
  float var = s2 * inv - mean * mean;
  stats[bg * 2] = mean;
  stats[bg * 2 + 1] = rsqrtf(var + 1e-5f);
}

// ---------------- GroupNorm normalize + transpose -> xn_T (B,T,C) bf16 ----------------
__global__ __launch_bounds__(256) void k_gn_norm(const float* __restrict__ x,
                                                 const float* __restrict__ scale,
                                                 const float* __restrict__ bias,
                                                 const float* __restrict__ stats,
                                                 unsigned short* __restrict__ xnT) {
  int ti = blockIdx.x;              // T/64
  int g  = blockIdx.y;              // 32
  int b  = blockIdx.z;              // 2
  int u  = threadIdx.x;
  int bg = b * 32 + g;
  float mean = stats[bg * 2], rstd = stats[bg * 2 + 1];
  __shared__ float L[32][65];
  int c_loc = u >> 3, tc = (u & 7) * 8;
  int cg = g * 32 + c_loc;
  const float* xp = x + ((size_t)b * Cdim + cg) * Tdim + ti * 64 + tc;
  float sc = scale[cg] * rstd;
  float bi = bias[cg] - mean * sc;  // xn = x*sc + bi
#pragma unroll
  for (int i = 0; i < 8; ++i) L[c_loc][tc + i] = xp[i] * sc + bi;
  __syncthreads();
  int t_loc = u >> 2, cc = (u & 3) * 8;
  s16x8 ov;
#pragma unroll
  for (int i = 0; i < 8; ++i) ov[i] = (short)f2bf(L[cc + i][t_loc]);
  *(s16x8*)&xnT[((size_t)b * Tdim + ti * 64 + t_loc) * Cdim + g * 32 + cc] = ov;
}

// ---------------- f32 -> bf16 convert ----------------
__global__ __launch_bounds__(256) void k_convert(const float* __restrict__ in,
                                                 unsigned short* __restrict__ out, int n4) {
  int i = blockIdx.x * 256 + threadIdx.x;
  if (i >= n4) return;
  f32x4 v = *(const f32x4*)(in + (size_t)i * 4);
  u16x4 o;
  o[0] = f2bf(v[0]); o[1] = f2bf(v[1]); o[2] = f2bf(v[2]); o[3] = f2bf(v[3]);
  *(u16x4*)(out + (size_t)i * 4) = o;
}

// ---------------- GEMM: out[t][o] = sum_c A[t][c] * Bw[o][c] (+bias) ----------------
template <int EPI>
__global__ __launch_bounds__(256) void k_gemm(const unsigned short* __restrict__ A,
                                              const unsigned short* __restrict__ Bw,
                                              const float* __restrict__ bias,
                                              unsigned short* __restrict__ outT,
                                              const unsigned short* __restrict__ xnT,
                                              float* __restrict__ out,
                                              int M, int N, int K) {
  int bx = blockIdx.x, by = blockIdx.y, bb = blockIdx.z;
  int tid = threadIdx.x;
  int lane = tid & 63, w = tid >> 6;
  int m0 = by * 128, n0 = bx * 128;
  const unsigned short* Ab = A + (size_t)bb * M * K;
  __shared__ short As[128][72];
  __shared__ short Bs[128][72];
  f32x4 acc[4][4] = {};
  int wm = (w >> 1) * 64, wn = (w & 1) * 64;
  int lr = lane & 15, lq = lane >> 4;

  for (int k0 = 0; k0 < K; k0 += 32) {
    s16x8 ra[2], rb[2];
#pragma unroll
    for (int p = 0; p < 2; ++p) {
      int u = tid + p * 256;
      int r = u >> 2, c = (u & 3) * 8;
      ra[p] = *(const s16x8*)(Ab + (size_t)(m0 + r) * K + k0 + c);
      rb[p] = *(const s16x8*)(Bw + (size_t)(n0 + r) * K + k0 + c);
    }
    __syncthreads();
#pragma unroll
    for (int p = 0; p < 2; ++p) {
      int u = tid + p * 256;
      int r = u >> 2, c = (u & 3) * 8;
      *(s16x8*)&As[r][c] = ra[p];
      *(s16x8*)&Bs[r][c] = rb[p];
    }
    __syncthreads();
    s16x8 af[4], bfr[4];
#pragma unroll
    for (int m = 0; m < 4; ++m) af[m] = *(const s16x8*)&As[wm + m * 16 + lr][lq * 8];
#pragma unroll
    for (int n = 0; n < 4; ++n) bfr[n] = *(const s16x8*)&Bs[wn + n * 16 + lr][lq * 8];
#pragma unroll
    for (int m = 0; m < 4; ++m)
#pragma unroll
      for (int n = 0; n < 4; ++n)
        acc[m][n] = __builtin_amdgcn_mfma_f32_16x16x32_bf16(af[m], bfr[n], acc[m][n], 0, 0, 0);
  }

  if constexpr (EPI == 0) {
#pragma unroll
    for (int n = 0; n < 4; ++n) {
      int col = n0 + wn + n * 16 + lr;
      float bv = bias[col];
#pragma unroll
      for (int m = 0; m < 4; ++m) {
        int rowb = m0 + wm + m * 16 + lq * 4;
#pragma unroll
        for (int j = 0; j < 4; ++j)
          outT[((size_t)bb * M + rowb + j) * N + col] = f2bf(acc[m][n][j] + bv);
      }
    }
  } else {
#pragma unroll
    for (int n = 0; n < 4; ++n) {
      int col = n0 + wn + n * 16 + lr;    // output channel o
      float bv = bias[col];
#pragma unroll
      for (int m = 0; m < 4; ++m) {
        int rowb = m0 + wm + m * 16 + lq * 4;  // t base (4 consecutive)
        f32x4 v;
#pragma unroll
        for (int j = 0; j < 4; ++j)
          v[j] = acc[m][n][j] + bv + bf2f(xnT[((size_t)bb * M + rowb + j) * Cdim + col]);
        *(f32x4*)&out[((size_t)bb * N + col) * M + rowb] = v;
      }
    }
  }
}

// ---------------- Flash attention, 32x32 swapped-operand structure ----------------
// qkvT: (B, T, 3C), head h cols [h*192, h*192+192) = q|k|v each 64
// 4 waves x 32 q-rows = 128 q/block; KVBLK = 64; S^T = mfma(K,Q); O^T = mfma(V^T,P^T)
__global__ __launch_bounds__(256) void k_attn(const unsigned short* __restrict__ qkvT,
                                              const unsigned short* __restrict__ biasbf,
                                              unsigned short* __restrict__ aT) {
  int ti = blockIdx.x;              // q tile of 128 rows
  int bh = blockIdx.y;              // b*16 + h
  int b = bh >> 4, h = bh & 15;
  int tid = threadIdx.x, lane = tid & 63, w = tid >> 6;
  int r = lane & 31, hi = lane >> 5;
  int t0 = ti * 128;
  int q0 = t0 + w * 32;             // wave's q base
  int qg = q0 + r;                  // this lane's q row
  const unsigned short* hb = qkvT + ((size_t)b * Tdim) * C3 + h * 192;

  __shared__ __align__(16) char Ks[8192];   // [s][ch] 64x64 bf16, byte^=(s&7)<<4
  __shared__ __align__(16) char Vt[8192];   // [ch][s] 64x64 bf16, byte^=(ch&7)<<4

  // hoist Q (scaled by 0.125 = scale^2, exact power-of-2)
  s16x8 qf[4];
#pragma unroll
  for (int kb = 0; kb < 4; ++kb) {
    s16x8 raw = *(const s16x8*)(hb + (size_t)qg * C3 + kb * 16 + hi * 8);
#pragma unroll
    for (int j = 0; j < 8; ++j)
      qf[kb][j] = (short)f2bf(bf2f((unsigned short)raw[j]) * 0.125f);
  }

  f32x16 oacc[2];
#pragma unroll
  for (int c2 = 0; c2 < 2; ++c2)
#pragma unroll
    for (int e = 0; e < 16; ++e) oacc[c2][e] = 0.f;
  float mrow = -1e30f, lrowv = 0.f;

  int nt = 2 * ti + 2;
  for (int sj = 0; sj < nt; ++sj) {
    int s0 = sj * 64;
    bool active = (s0 <= q0 + 31);  // wave-uniform

    // ---- stage K/V (all threads) ----
    s16x8 kc[2], vc[2];
    int vs[2], vc0[2], ks[2], kcb[2];
#pragma unroll
    for (int p = 0; p < 2; ++p) {
      int u = tid + p * 256;
      ks[p] = u >> 3; kcb[p] = u & 7;
      kc[p] = *(const s16x8*)(hb + (size_t)(s0 + ks[p]) * C3 + 64 + kcb[p] * 8);
      vs[p] = u & 63; vc0[p] = (u >> 6) * 8;
      vc[p] = *(const s16x8*)(hb + (size_t)(s0 + vs[p]) * C3 + 128 + vc0[p]);
    }
    // bias loads (wave-uniform guard)
    u16x4 bv[8];
    if (active) {
#pragma unroll
      for (int st = 0; st < 2; ++st)
#pragma unroll
        for (int rg = 0; rg < 4; ++rg)
          bv[st * 4 + rg] = *(const u16x4*)(biasbf + (size_t)qg * Tdim + s0 + st * 32 + rg * 8 + 4 * hi);
    }
    __syncthreads();                 // previous tile's LDS reads complete
#pragma unroll
    for (int p = 0; p < 2; ++p) {
      *(s16x8*)(Ks + ks[p] * 128 + ((kcb[p] * 16) ^ ((ks[p] & 7) << 4))) = kc[p];
#pragma unroll
      for (int i = 0; i < 8; ++i)
        *(short*)(Vt + (vc0[p] + i) * 128 + ((vs[p] * 2) ^ (((vc0[p] + i) & 7) << 4))) = vc[p][i];
    }
    __syncthreads();
    if (!active) continue;          // barriers balanced; skip compute only

    // ---- S^T = K * Q^T : lane holds col q=r, rows via reg ----
    f32x16 sa[2];
#pragma unroll
    for (int st = 0; st < 2; ++st) {
#pragma unroll
      for (int e = 0; e < 16; ++e) sa[st][e] = 0.f;
      int row = st * 32 + r;
      int swz = (row & 7) << 4;
#pragma unroll
      for (int kb = 0; kb < 4; ++kb) {
        s16x8 kf = *(const s16x8*)(Ks + row * 128 + ((kb * 32 + hi * 16) ^ swz));
        sa[st] = __builtin_amdgcn_mfma_f32_32x32x16_bf16(kf, qf[kb], sa[st], 0, 0, 0);
      }
    }
    // ---- bias + causal mask ----
    bool need_mask = (s0 + 63 > q0);
#pragma unroll
    for (int st = 0; st < 2; ++st)
#pragma unroll
      for (int rg = 0; rg < 4; ++rg) {
        int sbase = s0 + st * 32 + rg * 8 + 4 * hi;
#pragma unroll
        for (int c = 0; c < 4; ++c) {
          int e = rg * 4 + c;
          float x = sa[st][e] + bf2f(bv[st * 4 + rg][c]);
          sa[st][e] = (need_mask && (sbase + c > qg)) ? -1e30f : x;
        }
      }
    // ---- online softmax (row fully in lane pair l, l^32) ----
    float t8[8];
#pragma unroll
    for (int e = 0; e < 8; ++e)
      t8[e] = fmaxf(fmaxf(sa[0][e], sa[0][e + 8]), fmaxf(sa[1][e], sa[1][e + 8]));
    float pm = fmaxf(fmaxf(fmaxf(t8[0], t8[1]), fmaxf(t8[2], t8[3])),
                     fmaxf(fmaxf(t8[4], t8[5]), fmaxf(t8[6], t8[7])));
    pm = fmaxf(pm, __shfl_xor(pm, 32));
    float mnew = fmaxf(mrow, pm);
    float al = __expf(mrow - mnew);
    mrow = mnew;
#pragma unroll
    for (int st = 0; st < 2; ++st)
#pragma unroll
      for (int e = 0; e < 16; ++e) sa[st][e] = __expf(sa[st][e] - mnew);
    float s8[8];
#pragma unroll
    for (int e = 0; e < 8; ++e)
      s8[e] = (sa[0][e] + sa[0][e + 8]) + (sa[1][e] + sa[1][e + 8]);
    float rsum = ((s8[0] + s8[1]) + (s8[2] + s8[3])) + ((s8[4] + s8[5]) + (s8[6] + s8[7]));
    rsum += __shfl_xor(rsum, 32);
    lrowv = lrowv * al + rsum;
#pragma unroll
    for (int c2 = 0; c2 < 2; ++c2)
#pragma unroll
      for (int e = 0; e < 16; ++e) oacc[c2][e] *= al;

    // ---- P -> bf16 B-fragments (pack + cross-half exchange) ----
    s16x8 pfr[4];
#pragma unroll
    for (int sblk = 0; sblk < 4; ++sblk) {
      const int st = sblk >> 1, sb = sblk & 1;
      uint32_t a0 = packbf(sa[st][(sb * 2) * 4 + 0], sa[st][(sb * 2) * 4 + 1]);
      uint32_t a1 = packbf(sa[st][(sb * 2) * 4 + 2], sa[st][(sb * 2) * 4 + 3]);
      uint32_t b0 = packbf(sa[st][(sb * 2 + 1) * 4 + 0], sa[st][(sb * 2 + 1) * 4 + 1]);
      uint32_t b1 = packbf(sa[st][(sb * 2 + 1) * 4 + 2], sa[st][(sb * 2 + 1) * 4 + 3]);
      uint32_t xa0 = (uint32_t)__shfl_xor((int)a0, 32);
      uint32_t xa1 = (uint32_t)__shfl_xor((int)a1, 32);
      uint32_t xb0 = (uint32_t)__shfl_xor((int)b0, 32);
      uint32_t xb1 = (uint32_t)__shfl_xor((int)b1, 32);
      union { i32x4 i; s16x8 s; } u;
      u.i[0] = (int)(hi ? xb0 : a0);
      u.i[1] = (int)(hi ? xb1 : a1);
      u.i[2] = (int)(hi ? b0 : xa0);
      u.i[3] = (int)(hi ? b1 : xa1);
      pfr[sblk] = u.s;
    }
    // ---- O^T += V^T * P^T ----
#pragma unroll
    for (int c2 = 0; c2 < 2; ++c2) {
      int row = c2 * 32 + r;
      int swz = (row & 7) << 4;
#pragma unroll
      for (int sblk = 0; sblk < 4; ++sblk) {
        s16x8 vf = *(const s16x8*)(Vt + row * 128 + ((sblk * 32 + hi * 16) ^ swz));
        oacc[c2] = __builtin_amdgcn_mfma_f32_32x32x16_bf16(vf, pfr[sblk], oacc[c2], 0, 0, 0);
      }
    }
  }

  // ---- write a^T (B,T,C) ----
  float inv = 1.0f / lrowv;
#pragma unroll
  for (int c2 = 0; c2 < 2; ++c2)
#pragma unroll
    for (int reg = 0; reg < 16; ++reg) {
      int ch = h * 64 + c2 * 32 + (reg & 3) + 8 * (reg >> 2) + 4 * hi;
      aT[((size_t)b * Tdim + qg) * Cdim + ch] = f2bf(oacc[c2][reg] * inv);
    }
}

extern "C" void kernel_launch(void* const* d_in, const int* in_sizes, int n_in,
                              void* d_out, int out_size, void* d_ws, size_t ws_size,
                              hipStream_t stream) {
  const float* x        = (const float*)d_in[0];
  // d_in[1] = mask (bool tril) — causality applied analytically, ignored
  const float* qk_bias  = (const float*)d_in[2];
  const float* gn_scale = (const float*)d_in[3];
  const float* gn_bias  = (const float*)d_in[4];
  const float* qkv_w    = (const float*)d_in[5];
  const float* qkv_b    = (const float*)d_in[6];
  const float* proj_w   = (const float*)d_in[7];
  const float* proj_b   = (const float*)d_in[8];
  float* out = (float*)d_out;

  char* ws = (char*)d_ws;
  unsigned short* xnT   = (unsigned short*)(ws);                      //  8 MiB (B,T,C)
  unsigned short* qkvT  = (unsigned short*)(ws + ( 8ull << 20));      // 24 MiB (B,T,3C)
  unsigned short* aT    = (unsigned short*)(ws + (32ull << 20));      //  8 MiB (B,T,C)
  unsigned short* wqkv  = (unsigned short*)(ws + (40ull << 20));      //  6 MiB (3C,C)
  unsigned short* wproj = (unsigned short*)(ws + (46ull << 20));      //  2 MiB (C,C)
  unsigned short* biasb = (unsigned short*)(ws + (48ull << 20));      //  8 MiB (T,T)
  float* part  = (float*)(ws + (56ull << 20));                        //  4 KiB
  float* stats = (float*)(ws + (56ull << 20) + 8192);                 //  512 B

  k_gn_partial<<<512, 256, 0, stream>>>(x, part);
  k_gn_final<<<1, 64, 0, stream>>>(part, stats);
  k_gn_norm<<<dim3(32, 32, 2), 256, 0, stream>>>(x, gn_scale, gn_bias, stats, xnT);

  k_convert<<<(3072 * 1024 / 4 + 255) / 256, 256, 0, stream>>>(qkv_w, wqkv, 3072 * 1024 / 4);
  k_convert<<<(1024 * 1024 / 4 + 255) / 256, 256, 0, stream>>>(proj_w, wproj, 1024 * 1024 / 4);
  k_convert<<<(2048 * 2048 / 4 + 255) / 256, 256, 0, stream>>>(qk_bias, biasb, 2048 * 2048 / 4);

  // QKV: M=T=2048, N=3C=3072, K=C=1024, batched over B
  k_gemm<0><<<dim3(24, 16, 2), 256, 0, stream>>>(xnT, wqkv, qkv_b, qkvT, nullptr, nullptr,
                                                 2048, 3072, 1024);
  k_attn<<<dim3(16, 32), 256, 0, stream>>>(qkvT, biasb, aT);
  // proj + residual: M=2048, N=1024, K=1024
  k_gemm<1><<<dim3(8, 16, 2), 256, 0, stream>>>(aT, wproj, proj_b, nullptr, xnT, out,
                                                2048, 1024, 1024);
}

// Round 3
// 191.671 us; speedup vs baseline: 1.1467x; 1.0664x over previous
//
#include <hip/hip_runtime.h>
#include <stdint.h>

#define Tdim 2048
#define Cdim 1024
#define C3   3072

typedef __attribute__((ext_vector_type(8))) short s16x8;
typedef __attribute__((ext_vector_type(4))) unsigned short u16x4;
typedef __attribute__((ext_vector_type(4))) float f32x4;
typedef __attribute__((ext_vector_type(16))) float f32x16;
typedef __attribute__((ext_vector_type(4))) int i32x4;

__device__ __forceinline__ unsigned short f2bf(float f) {
  uint32_t u = __float_as_uint(f);
  return (unsigned short)((u + 0x7FFFu + ((u >> 16) & 1u)) >> 16);
}
__device__ __forceinline__ float bf2f(unsigned short s) {
  return __uint_as_float(((uint32_t)s) << 16);
}
__device__ __forceinline__ uint32_t cvtpk(float lo, float hi) {
  uint32_t r;
  asm("v_cvt_pk_bf16_f32 %0, %1, %2" : "=v"(r) : "v"(lo), "v"(hi));
  return r;
}

// ---------------- GroupNorm stats (two-stage, deterministic) ----------------
__global__ __launch_bounds__(256) void k_gn_partial(const float* __restrict__ x,
                                                    float* __restrict__ part) {
  int bid = blockIdx.x;             // [0,512) = bg*8 + tchunk
  int bg = bid >> 3, tc = bid & 7;
  const float* xp = x + ((size_t)(bg >> 5) * Cdim + (size_t)(bg & 31) * 32) * Tdim + tc * 256;
  int u = threadIdx.x;
  float s1 = 0.f, s2 = 0.f;
#pragma unroll
  for (int i = 0; i < 32; ++i) {
    int e = u + i * 256;            // 32c x 256t tile
    float v = xp[(size_t)(e >> 8) * Tdim + (e & 255)];
    s1 += v; s2 += v * v;
  }
  for (int m = 1; m < 64; m <<= 1) { s1 += __shfl_xor(s1, m); s2 += __shfl_xor(s2, m); }
  __shared__ float r1[4], r2[4];
  int w = u >> 6;
  if ((u & 63) == 0) { r1[w] = s1; r2[w] = s2; }
  __syncthreads();
  if (u == 0) {
    part[bid * 2]     = r1[0] + r1[1] + r1[2] + r1[3];
    part[bid * 2 + 1] = r2[0] + r2[1] + r2[2] + r2[3];
  }
}

__global__ void k_gn_final(const float* __restrict__ part, float* __restrict__ stats) {
  int bg = threadIdx.x;             // 64 threads
  float s1 = 0.f, s2 = 0.f;
  for (int j = 0; j < 8; ++j) { s1 += part[(bg * 8 + j) * 2]; s2 += part[(bg * 8 + j) * 2 + 1]; }
  const float inv = 1.f / 65536.f;
  float mean = s1 * inv;
  float var = s2 * inv - mean * mean;
  stats[bg * 2] = mean;
  stats[bg * 2 + 1] = rsqrtf(var + 1e-5f);
}

// ---------------- GroupNorm normalize + transpose -> xn_T (B,T,C) bf16 ----------------
__global__ __launch_bounds__(256) void k_gn_norm(const float* __restrict__ x,
                                                 const float* __restrict__ scale,
                                                 const float* __restrict__ bias,
                                                 const float* __restrict__ stats,
                                                 unsigned short* __restrict__ xnT) {
  int ti = blockIdx.x;              // T/64
  int g  = blockIdx.y;              // 32
  int b  = blockIdx.z;              // 2
  int u  = threadIdx.x;
  int bg = b * 32 + g;
  float mean = stats[bg * 2], rstd = stats[bg * 2 + 1];
  __shared__ float L[32][65];
  int c_loc = u >> 3, tc = (u & 7) * 8;
  int cg = g * 32 + c_loc;
  const float* xp = x + ((size_t)b * Cdim + cg) * Tdim + ti * 64 + tc;
  float sc = scale[cg] * rstd;
  float bi = bias[cg] - mean * sc;  // xn = x*sc + bi
#pragma unroll
  for (int i = 0; i < 8; ++i) L[c_loc][tc + i] = xp[i] * sc + bi;
  __syncthreads();
  int t_loc = u >> 2, cc = (u & 3) * 8;
  s16x8 ov;
#pragma unroll
  for (int i = 0; i < 8; ++i) ov[i] = (short)f2bf(L[cc + i][t_loc]);
  *(s16x8*)&xnT[((size_t)b * Tdim + ti * 64 + t_loc) * Cdim + g * 32 + cc] = ov;
}

// ---------------- f32 -> bf16 convert ----------------
__global__ __launch_bounds__(256) void k_convert(const float* __restrict__ in,
                                                 unsigned short* __restrict__ out, int n4) {
  int i = blockIdx.x * 256 + threadIdx.x;
  if (i >= n4) return;
  f32x4 v = *(const f32x4*)(in + (size_t)i * 4);
  u16x4 o;
  o[0] = f2bf(v[0]); o[1] = f2bf(v[1]); o[2] = f2bf(v[2]); o[3] = f2bf(v[3]);
  *(u16x4*)(out + (size_t)i * 4) = o;
}

// ---------------- bias convert + transpose: biasT[s][t] = bf16(bias[t][s]) ----------------
__global__ __launch_bounds__(256) void k_bias_t(const float* __restrict__ in,
                                                unsigned short* __restrict__ outT) {
  int bs0 = blockIdx.x * 64;        // s tile (output rows)
  int bt0 = blockIdx.y * 64;        // t tile (output cols)
  __shared__ unsigned short L[64][65];
  int tid = threadIdx.x;
  int tl = tid >> 2, c0 = (tid & 3) * 16;
  const float* ip = in + (size_t)(bt0 + tl) * Tdim + bs0 + c0;   // row t, cols s
#pragma unroll
  for (int i = 0; i < 16; ++i) L[tl][c0 + i] = f2bf(ip[i]);
  __syncthreads();
  unsigned short* op = outT + (size_t)(bs0 + tl) * Tdim + bt0 + c0;  // row s, cols t
#pragma unroll
  for (int i = 0; i < 16; i += 4) {
    u16x4 o;
    o[0] = L[c0 + i][tl]; o[1] = L[c0 + i + 1][tl];
    o[2] = L[c0 + i + 2][tl]; o[3] = L[c0 + i + 3][tl];
    *(u16x4*)(op + i) = o;
  }
}

// ---------------- GEMM: out[t][o] = sum_c A[t][c] * Bw[o][c] (+bias) ----------------
template <int EPI>
__global__ __launch_bounds__(256) void k_gemm(const unsigned short* __restrict__ A,
                                              const unsigned short* __restrict__ Bw,
                                              const float* __restrict__ bias,
                                              unsigned short* __restrict__ outT,
                                              const unsigned short* __restrict__ xnT,
                                              float* __restrict__ out,
                                              int M, int N, int K) {
  int bx = blockIdx.x, by = blockIdx.y, bb = blockIdx.z;
  int tid = threadIdx.x;
  int lane = tid & 63, w = tid >> 6;
  int m0 = by * 128, n0 = bx * 128;
  const unsigned short* Ab = A + (size_t)bb * M * K;
  __shared__ short As[128][72];
  __shared__ short Bs[128][72];
  f32x4 acc[4][4] = {};
  int wm = (w >> 1) * 64, wn = (w & 1) * 64;
  int lr = lane & 15, lq = lane >> 4;

  for (int k0 = 0; k0 < K; k0 += 32) {
    s16x8 ra[2], rb[2];
#pragma unroll
    for (int p = 0; p < 2; ++p) {
      int u = tid + p * 256;
      int r = u >> 2, c = (u & 3) * 8;
      ra[p] = *(const s16x8*)(Ab + (size_t)(m0 + r) * K + k0 + c);
      rb[p] = *(const s16x8*)(Bw + (size_t)(n0 + r) * K + k0 + c);
    }
    __syncthreads();
#pragma unroll
    for (int p = 0; p < 2; ++p) {
      int u = tid + p * 256;
      int r = u >> 2, c = (u & 3) * 8;
      *(s16x8*)&As[r][c] = ra[p];
      *(s16x8*)&Bs[r][c] = rb[p];
    }
    __syncthreads();
    s16x8 af[4], bfr[4];
#pragma unroll
    for (int m = 0; m < 4; ++m) af[m] = *(const s16x8*)&As[wm + m * 16 + lr][lq * 8];
#pragma unroll
    for (int n = 0; n < 4; ++n) bfr[n] = *(const s16x8*)&Bs[wn + n * 16 + lr][lq * 8];
#pragma unroll
    for (int m = 0; m < 4; ++m)
#pragma unroll
      for (int n = 0; n < 4; ++n)
        acc[m][n] = __builtin_amdgcn_mfma_f32_16x16x32_bf16(af[m], bfr[n], acc[m][n], 0, 0, 0);
  }

  if constexpr (EPI == 0) {
#pragma unroll
    for (int n = 0; n < 4; ++n) {
      int col = n0 + wn + n * 16 + lr;
      float bv = bias[col];
#pragma unroll
      for (int m = 0; m < 4; ++m) {
        int rowb = m0 + wm + m * 16 + lq * 4;
#pragma unroll
        for (int j = 0; j < 4; ++j)
          outT[((size_t)bb * M + rowb + j) * N + col] = f2bf(acc[m][n][j] + bv);
      }
    }
  } else {
#pragma unroll
    for (int n = 0; n < 4; ++n) {
      int col = n0 + wn + n * 16 + lr;    // output channel o
      float bv = bias[col];
#pragma unroll
      for (int m = 0; m < 4; ++m) {
        int rowb = m0 + wm + m * 16 + lq * 4;  // t base (4 consecutive)
        f32x4 v;
#pragma unroll
        for (int j = 0; j < 4; ++j)
          v[j] = acc[m][n][j] + bv + bf2f(xnT[((size_t)bb * M + rowb + j) * Cdim + col]);
        *(f32x4*)&out[((size_t)bb * N + col) * M + rowb] = v;
      }
    }
  }
}

// ---------------- Flash attention, 32x32 swapped, prefetch + dbuf + LPT ----------------
__global__ __launch_bounds__(256, 2) void k_attn(const unsigned short* __restrict__ qkvT,
                                                 const unsigned short* __restrict__ biasT,
                                                 unsigned short* __restrict__ aT) {
  int ti = 15 - (int)blockIdx.x;    // LPT: heaviest q-tiles dispatch first
  int bh = blockIdx.y;              // b*16 + h
  int b = bh >> 4, h = bh & 15;
  int tid = threadIdx.x, lane = tid & 63, w = tid >> 6;
  int r = lane & 31, hi = lane >> 5;
  int q0 = ti * 128 + w * 32;       // wave's q base
  int qg = q0 + r;                  // this lane's q row
  const unsigned short* hb = qkvT + ((size_t)b * Tdim) * C3 + h * 192;
  const unsigned short* bT = biasT + qg;   // column base, stride Tdim

  __shared__ __align__(16) char Ks[2][8192];   // [s][ch] 64x64 bf16, byte^=(s&7)<<4
  __shared__ __align__(16) char Vt[2][8192];   // [ch][s] 64x64 bf16, byte^=(ch&7)<<4

  // hoist Q (scaled by 0.125 = scale^2, exact power-of-2)
  s16x8 qf[4];
#pragma unroll
  for (int kb = 0; kb < 4; ++kb) {
    s16x8 raw = *(const s16x8*)(hb + (size_t)qg * C3 + kb * 16 + hi * 8);
#pragma unroll
    for (int j = 0; j < 8; ++j)
      qf[kb][j] = (short)f2bf(bf2f((unsigned short)raw[j]) * 0.125f);
  }

  // staging thread geometry (fixed across iterations)
  int ksr[2], kcb[2], vsr[2], vc0[2];
#pragma unroll
  for (int p = 0; p < 2; ++p) {
    int u = tid + p * 256;
    ksr[p] = u >> 3; kcb[p] = u & 7;
    vsr[p] = u & 63; vc0[p] = (u >> 6) * 8;
  }
  s16x8 kc[2], vc[2];
  unsigned short bs[2][16];

  auto issue_kv = [&](int s0) {
#pragma unroll
    for (int p = 0; p < 2; ++p) {
      kc[p] = *(const s16x8*)(hb + (size_t)(s0 + ksr[p]) * C3 + 64 + kcb[p] * 8);
      vc[p] = *(const s16x8*)(hb + (size_t)(s0 + vsr[p]) * C3 + 128 + vc0[p]);
    }
  };
  auto issue_bias = [&](int s0) {
#pragma unroll
    for (int st = 0; st < 2; ++st)
#pragma unroll
      for (int e = 0; e < 16; ++e) {
        int s = s0 + st * 32 + (e & 3) + 8 * (e >> 2) + 4 * hi;
        bs[st][e] = bT[(size_t)s * Tdim];
      }
  };

  issue_kv(0);
  issue_bias(0);

  f32x16 oacc[2];
#pragma unroll
  for (int c2 = 0; c2 < 2; ++c2)
#pragma unroll
    for (int e = 0; e < 16; ++e) oacc[c2][e] = 0.f;
  float mrow = -1e30f, lrowv = 0.f;

  int nt = 2 * ti + 2;
  for (int sj = 0; sj < nt; ++sj) {
    int cur = sj & 1;
    char* Kc = &Ks[cur][0];
    char* Vc = &Vt[cur][0];
    // ---- LDS write from prefetch regs (implicit vmcnt wait) ----
#pragma unroll
    for (int p = 0; p < 2; ++p) {
      *(s16x8*)(Kc + ksr[p] * 128 + ((kcb[p] * 16) ^ ((ksr[p] & 7) << 4))) = kc[p];
#pragma unroll
      for (int i = 0; i < 8; ++i)
        *(short*)(Vc + (vc0[p] + i) * 128 + ((vsr[p] * 2) ^ (((vc0[p] + i) & 7) << 4))) = vc[p][i];
    }
    __syncthreads();
    // ---- prefetch next K/V tile (hidden under this tile's compute) ----
    if (sj + 1 < nt) issue_kv((sj + 1) * 64);

    int s0 = sj * 64;
    bool active = (s0 <= q0 + 31);  // wave-uniform, monotone decreasing
    if (active) {
      // ---- S^T = K * Q^T ----
      f32x16 sa[2];
#pragma unroll
      for (int st = 0; st < 2; ++st) {
#pragma unroll
        for (int e = 0; e < 16; ++e) sa[st][e] = 0.f;
        int row = st * 32 + r;
        int swz = (row & 7) << 4;
#pragma unroll
        for (int kb = 0; kb < 4; ++kb) {
          s16x8 kf = *(const s16x8*)(Kc + row * 128 + ((kb * 32 + hi * 16) ^ swz));
          sa[st] = __builtin_amdgcn_mfma_f32_32x32x16_bf16(kf, qf[kb], sa[st], 0, 0, 0);
        }
      }
      // ---- bias + causal mask ----
      bool need_mask = (s0 + 63 > q0);
#pragma unroll
      for (int st = 0; st < 2; ++st)
#pragma unroll
        for (int e = 0; e < 16; ++e) {
          int s = s0 + st * 32 + (e & 3) + 8 * (e >> 2) + 4 * hi;
          float x = sa[st][e] + bf2f(bs[st][e]);
          sa[st][e] = (need_mask && s > qg) ? -1e30f : x;
        }
      // ---- prefetch next bias tile (after bs consumed) ----
      if (sj + 1 < nt && (sj + 1) * 64 <= q0 + 31) issue_bias((sj + 1) * 64);
      // ---- online softmax with defer-max (THR=8) ----
      float t8[8];
#pragma unroll
      for (int e = 0; e < 8; ++e)
        t8[e] = fmaxf(fmaxf(sa[0][e], sa[0][e + 8]), fmaxf(sa[1][e], sa[1][e + 8]));
      float pm = fmaxf(fmaxf(fmaxf(t8[0], t8[1]), fmaxf(t8[2], t8[3])),
                       fmaxf(fmaxf(t8[4], t8[5]), fmaxf(t8[6], t8[7])));
      pm = fmaxf(pm, __shfl_xor(pm, 32));
      if (!__all(pm <= mrow + 8.0f)) {
        float mnew = fmaxf(mrow, pm);
        float al = __expf(mrow - mnew);
        mrow = mnew;
        lrowv *= al;
#pragma unroll
        for (int c2 = 0; c2 < 2; ++c2)
#pragma unroll
          for (int e = 0; e < 16; ++e) oacc[c2][e] *= al;
      }
#pragma unroll
      for (int st = 0; st < 2; ++st)
#pragma unroll
        for (int e = 0; e < 16; ++e) sa[st][e] = __expf(sa[st][e] - mrow);
      float s8[8];
#pragma unroll
      for (int e = 0; e < 8; ++e)
        s8[e] = (sa[0][e] + sa[0][e + 8]) + (sa[1][e] + sa[1][e + 8]);
      float rsum = ((s8[0] + s8[1]) + (s8[2] + s8[3])) + ((s8[4] + s8[5]) + (s8[6] + s8[7]));
      rsum += __shfl_xor(rsum, 32);
      lrowv += rsum;

      // ---- P -> bf16 B-fragments (cvt_pk + cross-half exchange) ----
      s16x8 pfr[4];
#pragma unroll
      for (int sblk = 0; sblk < 4; ++sblk) {
        const int st = sblk >> 1, sb = sblk & 1;
        uint32_t a0 = cvtpk(sa[st][sb * 8 + 0], sa[st][sb * 8 + 1]);
        uint32_t a1 = cvtpk(sa[st][sb * 8 + 2], sa[st][sb * 8 + 3]);
        uint32_t b0 = cvtpk(sa[st][sb * 8 + 4], sa[st][sb * 8 + 5]);
        uint32_t b1 = cvtpk(sa[st][sb * 8 + 6], sa[st][sb * 8 + 7]);
        uint32_t xa0 = (uint32_t)__shfl_xor((int)a0, 32);
        uint32_t xa1 = (uint32_t)__shfl_xor((int)a1, 32);
        uint32_t xb0 = (uint32_t)__shfl_xor((int)b0, 32);
        uint32_t xb1 = (uint32_t)__shfl_xor((int)b1, 32);
        union { i32x4 i; s16x8 s; } u;
        u.i[0] = (int)(hi ? xb0 : a0);
        u.i[1] = (int)(hi ? xb1 : a1);
        u.i[2] = (int)(hi ? b0 : xa0);
        u.i[3] = (int)(hi ? b1 : xa1);
        pfr[sblk] = u.s;
      }
      // ---- O^T += V^T * P^T ----
#pragma unroll
      for (int c2 = 0; c2 < 2; ++c2) {
        int row = c2 * 32 + r;
        int swz = (row & 7) << 4;
#pragma unroll
        for (int sblk = 0; sblk < 4; ++sblk) {
          s16x8 vf = *(const s16x8*)(Vc + row * 128 + ((sblk * 32 + hi * 16) ^ swz));
          oacc[c2] = __builtin_amdgcn_mfma_f32_32x32x16_bf16(vf, pfr[sblk], oacc[c2], 0, 0, 0);
        }
      }
    }
  }

  // ---- write a^T (B,T,C) ----
  float inv = 1.0f / lrowv;
#pragma unroll
  for (int c2 = 0; c2 < 2; ++c2)
#pragma unroll
    for (int reg = 0; reg < 16; ++reg) {
      int ch = h * 64 + c2 * 32 + (reg & 3) + 8 * (reg >> 2) + 4 * hi;
      aT[((size_t)b * Tdim + qg) * Cdim + ch] = f2bf(oacc[c2][reg] * inv);
    }
}

extern "C" void kernel_launch(void* const* d_in, const int* in_sizes, int n_in,
                              void* d_out, int out_size, void* d_ws, size_t ws_size,
                              hipStream_t stream) {
  const float* x        = (const float*)d_in[0];
  // d_in[1] = mask (bool tril) — causality applied analytically, ignored
  const float* qk_bias  = (const float*)d_in[2];
  const float* gn_scale = (const float*)d_in[3];
  const float* gn_bias  = (const float*)d_in[4];
  const float* qkv_w    = (const float*)d_in[5];
  const float* qkv_b    = (const float*)d_in[6];
  const float* proj_w   = (const float*)d_in[7];
  const float* proj_b   = (const float*)d_in[8];
  float* out = (float*)d_out;

  char* ws = (char*)d_ws;
  unsigned short* xnT   = (unsigned short*)(ws);                      //  8 MiB (B,T,C)
  unsigned short* qkvT  = (unsigned short*)(ws + ( 8ull << 20));      // 24 MiB (B,T,3C)
  unsigned short* aT    = (unsigned short*)(ws + (32ull << 20));      //  8 MiB (B,T,C)
  unsigned short* wqkv  = (unsigned short*)(ws + (40ull << 20));      //  6 MiB (3C,C)
  unsigned short* wproj = (unsigned short*)(ws + (46ull << 20));      //  2 MiB (C,C)
  unsigned short* biasT = (unsigned short*)(ws + (48ull << 20));      //  8 MiB (T,T) transposed
  float* part  = (float*)(ws + (56ull << 20));                        //  4 KiB
  float* stats = (float*)(ws + (56ull << 20) + 8192);                 //  512 B

  k_gn_partial<<<512, 256, 0, stream>>>(x, part);
  k_gn_final<<<1, 64, 0, stream>>>(part, stats);
  k_gn_norm<<<dim3(32, 32, 2), 256, 0, stream>>>(x, gn_scale, gn_bias, stats, xnT);

  k_convert<<<(3072 * 1024 / 4 + 255) / 256, 256, 0, stream>>>(qkv_w, wqkv, 3072 * 1024 / 4);
  k_convert<<<(1024 * 1024 / 4 + 255) / 256, 256, 0, stream>>>(proj_w, wproj, 1024 * 1024 / 4);
  k_bias_t<<<dim3(32, 32), 256, 0, stream>>>(qk_bias, biasT);

  // QKV: M=T=2048, N=3C=3072, K=C=1024, batched over B
  k_gemm<0><<<dim3(24, 16, 2), 256, 0, stream>>>(xnT, wqkv, qkv_b, qkvT, nullptr, nullptr,
                                                 2048, 3072, 1024);
  k_attn<<<dim3(16, 32), 256, 0, stream>>>(qkvT, biasT, aT);
  // proj + residual: M=2048, N=1024, K=1024
  k_gemm<1><<<dim3(8, 16, 2), 256, 0, stream>>>(aT, wproj, proj_b, nullptr, xnT, out,
                                                2048, 1024, 1024);
}